// Round 6
// baseline (190.649 us; speedup 1.0000x reference)
//
#include <hip/hip_runtime.h>

#define N_B   64
#define T_S   32
#define DIM   12288          // 3*64*64
#define ROWS  2048           // N_B*T_S
#define NCOL  12             // used GEMM columns (3 obj * 4)
#define RPW   8              // rows per wave
#define WAVES 4
#define RPB   (RPW * WAVES)  // 32 rows per block
#define KSPL  8              // split-K factor
#define KSEG  (DIM / KSPL)   // 1536
#define JSTEP (KSEG / 256)   // 6 f4-steps per lane

// ---------------- Kernel 0: transpose used W columns -> Wt[c][k] -----------
__global__ __launch_bounds__(256) void k_tw(const float* __restrict__ W,
                                            float* __restrict__ Wt) {
    const int idx = blockIdx.x * 256 + threadIdx.x;   // 0 .. 147455
    const int c   = idx / DIM;
    const int k   = idx - c * DIM;
    const int cm  = ((c >> 2) << 3) | (c & 3);
    Wt[idx] = W[k * 24 + cm];
}

// ---------------- Kernel 1: split-K skinny GEMM, 32 rows/block -------------
// Grid: 512 blocks = 64 row-groups x 8 k-segments. Wave w owns 8 rows; all
// 4 waves share the same Wt addresses (L1). Wt L2 traffic = 73.7KB*512=38MB.
__global__ __launch_bounds__(256) void k_gemm(const float* __restrict__ x,
                                              const float* __restrict__ Wt,
                                              float* __restrict__ part) {
    const int rb   = blockIdx.x >> 3;      // row group (0..63)
    const int sg   = blockIdx.x & 7;       // k segment (0..7)
    const int tid  = threadIdx.x;
    const int wave = tid >> 6;
    const int lane = tid & 63;
    const int r0   = rb * RPB + wave * RPW;
    const int kb0  = sg * KSEG + lane * 4;

    float acc[RPW][NCOL];
#pragma unroll
    for (int r = 0; r < RPW; ++r)
#pragma unroll
        for (int c = 0; c < NCOL; ++c) acc[r][c] = 0.f;

#pragma unroll 1
    for (int j = 0; j < JSTEP; ++j) {
        const int kb = kb0 + j * 256;
        float4 xv[RPW];
#pragma unroll
        for (int r = 0; r < RPW; ++r)
            xv[r] = *(const float4*)(x + (size_t)(r0 + r) * DIM + kb);
#pragma unroll
        for (int c = 0; c < NCOL; ++c) {
            const float4 wv = *(const float4*)(Wt + (size_t)c * DIM + kb);
#pragma unroll
            for (int r = 0; r < RPW; ++r)
                acc[r][c] += xv[r].x * wv.x + xv[r].y * wv.y +
                             xv[r].z * wv.z + xv[r].w * wv.w;
        }
    }

    // wave butterfly: sum each of the 96 accumulators across 64 lanes
#pragma unroll
    for (int r = 0; r < RPW; ++r)
#pragma unroll
        for (int c = 0; c < NCOL; ++c) {
            float v = acc[r][c];
            v += __shfl_xor(v, 32, 64);
            v += __shfl_xor(v, 16, 64);
            v += __shfl_xor(v, 8, 64);
            v += __shfl_xor(v, 4, 64);
            v += __shfl_xor(v, 2, 64);
            v += __shfl_xor(v, 1, 64);
            acc[r][c] = v;
        }

    __shared__ float red[RPB * NCOL];      // 384 floats
    if (lane == 0) {
#pragma unroll
        for (int r = 0; r < RPW; ++r)
#pragma unroll
            for (int c = 0; c < NCOL; ++c)
                red[(wave * RPW + r) * NCOL + c] = acc[r][c];
    }
    __syncthreads();

#pragma unroll
    for (int i = tid; i < RPB * NCOL; i += 256)
        part[(size_t)sg * (ROWS * NCOL) + (size_t)rb * (RPB * NCOL) + i] = red[i];
}

// ---------------- Kernel 2: reduce split-K + bias + sigmoid constrain ------
// Also emits zmatch[t][b][6] (positions only) for the lane-per-batch matcher.
__global__ __launch_bounds__(256) void k_reduce(const float* __restrict__ part,
                                                const float* __restrict__ b_enc,
                                                float* __restrict__ zbuf,
                                                float* __restrict__ zmatch) {
    const int rc = blockIdx.x * 256 + threadIdx.x;    // 0..24575 = row*12+c
    float s = 0.f;
#pragma unroll
    for (int i = 0; i < KSPL; ++i) s += part[(size_t)i * (ROWS * NCOL) + rc];

    const int row = rc / NCOL;
    const int c   = rc - row * NCOL;
    const int o   = c >> 2;
    const int cp  = c & 3;
    s += b_enc[o * 8 + cp];
    const float sg = 1.f / (1.f + expf(-s));
    float v;
    if (cp == 0)      v = sg * 0.7f + 0.1f;
    else if (cp == 1) v = sg * 0.5f + 0.75f;
    else              v = (2.f * sg - 1.f) * 0.9f;
    zbuf[rc] = v;

    if (cp >= 2) {
        const int b = row >> 5;           // row = b*32 + t
        const int t = row & 31;
        zmatch[((size_t)t * 64 + b) * 6 + o * 2 + (cp - 2)] = v;
    }
}

// ---------------- Kernel 3: matcher — lane = batch, one wave ---------------
// Branchless per-lane serial walk over T; writes perm codes[t*64+b].
__global__ __launch_bounds__(64) void k_match(const float* __restrict__ zmatch,
                                              int* __restrict__ codes) {
    const int b = threadIdx.x;            // batch 0..63

    float px0 = zmatch[b * 6 + 0], py0 = zmatch[b * 6 + 1];
    float px1 = zmatch[b * 6 + 2], py1 = zmatch[b * 6 + 3];
    float px2 = zmatch[b * 6 + 4], py2 = zmatch[b * 6 + 5];

    auto amin3 = [](float a0, float a1, float a2) {
        int j = 0; float e = a0;
        if (a1 < e) { e = a1; j = 1; }
        if (a2 < e) { j = 2; }
        return j;
    };

    for (int t = 1; t < T_S; ++t) {
        const float* p = zmatch + ((size_t)t * 64 + b) * 6;
        const float cx0 = p[0], cy0 = p[1];
        const float cx1 = p[2], cy1 = p[3];
        const float cx2 = p[4], cy2 = p[5];

        float dx, dy;
        dx = px0 - cx0; dy = py0 - cy0; const float e00 = dx * dx + dy * dy;
        dx = px0 - cx1; dy = py0 - cy1; const float e01 = dx * dx + dy * dy;
        dx = px0 - cx2; dy = py0 - cy2; const float e02 = dx * dx + dy * dy;
        dx = px1 - cx0; dy = py1 - cy0; const float e10 = dx * dx + dy * dy;
        dx = px1 - cx1; dy = py1 - cy1; const float e11 = dx * dx + dy * dy;
        dx = px1 - cx2; dy = py1 - cy2; const float e12 = dx * dx + dy * dy;
        dx = px2 - cx0; dy = py2 - cy0; const float e20 = dx * dx + dy * dy;
        dx = px2 - cx1; dy = py2 - cy1; const float e21 = dx * dx + dy * dy;
        dx = px2 - cx2; dy = py2 - cy2; const float e22 = dx * dx + dy * dy;

        const int i0 = amin3(e00, e01, e02);   // greedy step 0 == fast i0
        const int i1 = amin3(e10, e11, e12);
        const int i2 = amin3(e20, e21, e22);

        // greedy (always computed; selected when fast path collides)
        float u0 = (i0 == 0) ? 1e12f : 0.f;
        float u1 = (i0 == 1) ? 1e12f : 0.f;
        float u2 = (i0 == 2) ? 1e12f : 0.f;
        const int g1 = amin3(e10 + u0, e11 + u1, e12 + u2);
        if (g1 == 0) u0 = 1e12f; else if (g1 == 1) u1 = 1e12f; else u2 = 1e12f;
        const int g2 = amin3(e20 + u0, e21 + u1, e22 + u2);

        const bool ok = (i1 != i0) && (i2 != i1) && (i0 != i2);
        const int f1 = ok ? i1 : g1;
        const int f2 = ok ? i2 : g2;

        codes[t * 64 + b] = i0 * 9 + f1 * 3 + f2;

        px0 = (i0 == 0) ? cx0 : (i0 == 1) ? cx1 : cx2;
        py0 = (i0 == 0) ? cy0 : (i0 == 1) ? cy1 : cy2;
        px1 = (f1 == 0) ? cx0 : (f1 == 1) ? cx1 : cx2;
        py1 = (f1 == 0) ? cy0 : (f1 == 1) ? cy1 : cy2;
        px2 = (f2 == 0) ? cx0 : (f2 == 1) ? cx1 : cx2;
        py2 = (f2 == 0) ? cy0 : (f2 == 1) ? cy1 : cy2;
    }
}

// ---------------- Kernel 4: apply perm + fix_supair + output ---------------
__global__ __launch_bounds__(64) void k_apply(const float* __restrict__ zbuf,
                                              const int* __restrict__ codes,
                                              float* __restrict__ out) {
    __shared__ float z[T_S * NCOL];
    __shared__ float zm[T_S * NCOL];
    __shared__ float zf[T_S * NCOL];
    __shared__ int   perm[T_S];
    const int b   = blockIdx.x;
    const int tid = threadIdx.x;

#pragma unroll
    for (int i = 0; i < 6; ++i)
        z[tid + 64 * i] = zbuf[b * 384 + tid + 64 * i];
    if (tid >= 1 && tid < T_S) perm[tid] = codes[tid * 64 + b];
    __syncthreads();

    // apply permutation
#pragma unroll
    for (int ii = 0; ii < 6; ++ii) {
        const int i  = tid + 64 * ii;
        const int t  = i / 12;
        const int j  = i - t * 12;
        const int k  = j >> 2;
        const int ch = j & 3;
        int p = k;
        if (t > 0) {
            const int code = perm[t];
            p = (k == 0) ? code / 9 : (k == 1) ? (code % 9) / 3 : code % 3;
        }
        zm[i] = z[t * 12 + p * 4 + ch];
    }
    __syncthreads();

    // fix_supair
#pragma unroll
    for (int ii = 0; ii < 6; ++ii) {
        const int i  = tid + 64 * ii;
        const int t  = i / 12;
        const int j  = i - t * 12;
        const int o  = j >> 2;
        const int cc = j & 1;
        const int mb = o * 4 + cc;
        const float pd = (t >= 1)  ? fabsf(zm[t * 12 + mb] - zm[(t - 1) * 12 + mb]) : 0.f;
        const float ad = (t <= 30) ? fabsf(zm[(t + 1) * 12 + mb] - zm[t * 12 + mb]) : 0.f;
        const bool  m  = (pd > 0.095f) && (ad > 0.095f);
        const float sm = (t >= 1 && t <= 30)
                             ? (zm[(t - 1) * 12 + j] + zm[(t + 1) * 12 + j]) * 0.5f
                             : 0.f;
        zf[i] = m ? sm : zm[t * 12 + j];
    }
    __syncthreads();

    // output (64, 31, 3, 4)
    for (int i = tid; i < 31 * 12; i += 64) {
        const int t  = i / 12;
        const int j  = i - t * 12;
        const int o  = j >> 2;
        const int c2 = j & 3;
        const int pb = o * 4 + 2 + (c2 & 1);
        float v;
        if (c2 < 2) v = zf[(t + 1) * 12 + pb] + 1.f;
        else        v = (zf[(t + 1) * 12 + pb] - zf[t * 12 + pb]) * 10.f;
        out[b * 372 + i] = v;
    }
}

extern "C" void kernel_launch(void* const* d_in, const int* in_sizes, int n_in,
                              void* d_out, int out_size, void* d_ws, size_t ws_size,
                              hipStream_t stream) {
    (void)in_sizes; (void)n_in; (void)out_size; (void)ws_size;
    const float* x     = (const float*)d_in[0];
    const float* W_enc = (const float*)d_in[1];
    const float* b_enc = (const float*)d_in[2];
    float* out  = (float*)d_out;

    float* zbuf   = (float*)d_ws;                   // 24576 floats
    float* Wt     = zbuf + ROWS * NCOL;             // 147456 floats
    float* part   = Wt + NCOL * DIM;                // 8*24576 floats
    float* zmatch = part + KSPL * ROWS * NCOL;      // 32*64*6 = 12288 floats
    int*   codes  = (int*)(zmatch + T_S * N_B * 6); // 2048 ints

    k_tw    <<<(NCOL * DIM) / 256, 256, 0, stream>>>(W_enc, Wt);
    k_gemm  <<<(ROWS / RPB) * KSPL, 256, 0, stream>>>(x, Wt, part);
    k_reduce<<<(ROWS * NCOL) / 256, 256, 0, stream>>>(part, b_enc, zbuf, zmatch);
    k_match <<<1, 64, 0, stream>>>(zmatch, codes);
    k_apply <<<N_B, 64, 0, stream>>>(zbuf, codes, out);
}

// Round 7
// 180.290 us; speedup vs baseline: 1.0575x; 1.0575x over previous
//
#include <hip/hip_runtime.h>

#define N_B   64
#define T_S   32
#define DIM   12288          // 3*64*64
#define ROWS  2048           // N_B*T_S
#define NCOL  12             // used GEMM columns (3 obj * 4)
#define RPW   4              // rows per wave
#define WAVES 4
#define RPB   (RPW * WAVES)  // 16 rows per block
#define KSPL  16             // split-K factor
#define KSEG  (DIM / KSPL)   // 768
#define JSTEP (KSEG / 256)   // 3 f4-steps per lane

// ---------------- Kernel 0: transpose used W columns -> Wt[c][k] -----------
__global__ __launch_bounds__(256) void k_tw(const float* __restrict__ W,
                                            float* __restrict__ Wt) {
    const int idx = blockIdx.x * 256 + threadIdx.x;   // 0 .. 147455
    const int c   = idx / DIM;
    const int k   = idx - c * DIM;
    const int cm  = ((c >> 2) << 3) | (c & 3);
    Wt[idx] = W[k * 24 + cm];
}

// ---------------- Kernel 1: split-K skinny GEMM, latency-tolerant ----------
// Grid: 2048 blocks = 128 row-groups x 16 k-segments, 16 waves/CU.
// All 12 x-loads (3 j-steps x 4 rows) hoisted -> 12 outstanding loads/wave;
// Wt loads are L1/L2 hits (all 4 waves of a block share addresses).
__global__ __launch_bounds__(256) void k_gemm(const float* __restrict__ x,
                                              const float* __restrict__ Wt,
                                              float* __restrict__ part) {
    const int rb   = blockIdx.x >> 4;      // row group (0..127)
    const int sg   = blockIdx.x & 15;      // k segment (0..15)
    const int tid  = threadIdx.x;
    const int wave = tid >> 6;
    const int lane = tid & 63;
    const int r0   = rb * RPB + wave * RPW;
    const int kb0  = sg * KSEG + lane * 4;

    // hoist ALL x loads: 12 independent global_load_dwordx4 in flight
    float4 xv[JSTEP][RPW];
#pragma unroll
    for (int j = 0; j < JSTEP; ++j)
#pragma unroll
        for (int r = 0; r < RPW; ++r)
            xv[j][r] = *(const float4*)(x + (size_t)(r0 + r) * DIM + kb0 + j * 256);

    float acc[RPW][NCOL];
#pragma unroll
    for (int r = 0; r < RPW; ++r)
#pragma unroll
        for (int c = 0; c < NCOL; ++c) acc[r][c] = 0.f;

#pragma unroll
    for (int j = 0; j < JSTEP; ++j) {
        const int kb = kb0 + j * 256;
#pragma unroll
        for (int c = 0; c < NCOL; ++c) {
            const float4 wv = *(const float4*)(Wt + (size_t)c * DIM + kb);
#pragma unroll
            for (int r = 0; r < RPW; ++r)
                acc[r][c] += xv[j][r].x * wv.x + xv[j][r].y * wv.y +
                             xv[j][r].z * wv.z + xv[j][r].w * wv.w;
        }
    }

    // wave butterfly: sum each accumulator across 64 lanes
#pragma unroll
    for (int r = 0; r < RPW; ++r)
#pragma unroll
        for (int c = 0; c < NCOL; ++c) {
            float v = acc[r][c];
            v += __shfl_xor(v, 32, 64);
            v += __shfl_xor(v, 16, 64);
            v += __shfl_xor(v, 8, 64);
            v += __shfl_xor(v, 4, 64);
            v += __shfl_xor(v, 2, 64);
            v += __shfl_xor(v, 1, 64);
            acc[r][c] = v;
        }

    __shared__ float red[RPB * NCOL];      // 192 floats
    if (lane == 0) {
#pragma unroll
        for (int r = 0; r < RPW; ++r)
#pragma unroll
            for (int c = 0; c < NCOL; ++c)
                red[(wave * RPW + r) * NCOL + c] = acc[r][c];
    }
    __syncthreads();

    if (tid < RPB * NCOL)
        part[(size_t)sg * (ROWS * NCOL) + (size_t)rb * (RPB * NCOL) + tid] = red[tid];
}

// ---------------- Kernel 2: reduce split-K + bias + sigmoid constrain ------
// Also emits zmatch[t][b][6] (positions only) for the lane-per-batch matcher.
__global__ __launch_bounds__(256) void k_reduce(const float* __restrict__ part,
                                                const float* __restrict__ b_enc,
                                                float* __restrict__ zbuf,
                                                float* __restrict__ zmatch) {
    const int rc = blockIdx.x * 256 + threadIdx.x;    // 0..24575 = row*12+c
    float s = 0.f;
#pragma unroll
    for (int i = 0; i < KSPL; ++i) s += part[(size_t)i * (ROWS * NCOL) + rc];

    const int row = rc / NCOL;
    const int c   = rc - row * NCOL;
    const int o   = c >> 2;
    const int cp  = c & 3;
    s += b_enc[o * 8 + cp];
    const float sg = 1.f / (1.f + expf(-s));
    float v;
    if (cp == 0)      v = sg * 0.7f + 0.1f;
    else if (cp == 1) v = sg * 0.5f + 0.75f;
    else              v = (2.f * sg - 1.f) * 0.9f;
    zbuf[rc] = v;

    if (cp >= 2) {
        const int b = row >> 5;           // row = b*32 + t
        const int t = row & 31;
        zmatch[((size_t)t * 64 + b) * 6 + o * 2 + (cp - 2)] = v;
    }
}

// ---------------- Kernel 3: matcher — lane = batch, one wave ---------------
__global__ __launch_bounds__(64) void k_match(const float* __restrict__ zmatch,
                                              int* __restrict__ codes) {
    const int b = threadIdx.x;            // batch 0..63

    float px0 = zmatch[b * 6 + 0], py0 = zmatch[b * 6 + 1];
    float px1 = zmatch[b * 6 + 2], py1 = zmatch[b * 6 + 3];
    float px2 = zmatch[b * 6 + 4], py2 = zmatch[b * 6 + 5];

    auto amin3 = [](float a0, float a1, float a2) {
        int j = 0; float e = a0;
        if (a1 < e) { e = a1; j = 1; }
        if (a2 < e) { j = 2; }
        return j;
    };

    for (int t = 1; t < T_S; ++t) {
        const float* p = zmatch + ((size_t)t * 64 + b) * 6;
        const float cx0 = p[0], cy0 = p[1];
        const float cx1 = p[2], cy1 = p[3];
        const float cx2 = p[4], cy2 = p[5];

        float dx, dy;
        dx = px0 - cx0; dy = py0 - cy0; const float e00 = dx * dx + dy * dy;
        dx = px0 - cx1; dy = py0 - cy1; const float e01 = dx * dx + dy * dy;
        dx = px0 - cx2; dy = py0 - cy2; const float e02 = dx * dx + dy * dy;
        dx = px1 - cx0; dy = py1 - cy0; const float e10 = dx * dx + dy * dy;
        dx = px1 - cx1; dy = py1 - cy1; const float e11 = dx * dx + dy * dy;
        dx = px1 - cx2; dy = py1 - cy2; const float e12 = dx * dx + dy * dy;
        dx = px2 - cx0; dy = py2 - cy0; const float e20 = dx * dx + dy * dy;
        dx = px2 - cx1; dy = py2 - cy1; const float e21 = dx * dx + dy * dy;
        dx = px2 - cx2; dy = py2 - cy2; const float e22 = dx * dx + dy * dy;

        const int i0 = amin3(e00, e01, e02);   // greedy step 0 == fast i0
        const int i1 = amin3(e10, e11, e12);
        const int i2 = amin3(e20, e21, e22);

        float u0 = (i0 == 0) ? 1e12f : 0.f;
        float u1 = (i0 == 1) ? 1e12f : 0.f;
        float u2 = (i0 == 2) ? 1e12f : 0.f;
        const int g1 = amin3(e10 + u0, e11 + u1, e12 + u2);
        if (g1 == 0) u0 = 1e12f; else if (g1 == 1) u1 = 1e12f; else u2 = 1e12f;
        const int g2 = amin3(e20 + u0, e21 + u1, e22 + u2);

        const bool ok = (i1 != i0) && (i2 != i1) && (i0 != i2);
        const int f1 = ok ? i1 : g1;
        const int f2 = ok ? i2 : g2;

        codes[t * 64 + b] = i0 * 9 + f1 * 3 + f2;

        px0 = (i0 == 0) ? cx0 : (i0 == 1) ? cx1 : cx2;
        py0 = (i0 == 0) ? cy0 : (i0 == 1) ? cy1 : cy2;
        px1 = (f1 == 0) ? cx0 : (f1 == 1) ? cx1 : cx2;
        py1 = (f1 == 0) ? cy0 : (f1 == 1) ? cy1 : cy2;
        px2 = (f2 == 0) ? cx0 : (f2 == 1) ? cx1 : cx2;
        py2 = (f2 == 0) ? cy0 : (f2 == 1) ? cy1 : cy2;
    }
}

// ---------------- Kernel 4: apply perm + fix_supair + output ---------------
__global__ __launch_bounds__(64) void k_apply(const float* __restrict__ zbuf,
                                              const int* __restrict__ codes,
                                              float* __restrict__ out) {
    __shared__ float z[T_S * NCOL];
    __shared__ float zm[T_S * NCOL];
    __shared__ float zf[T_S * NCOL];
    __shared__ int   perm[T_S];
    const int b   = blockIdx.x;
    const int tid = threadIdx.x;

#pragma unroll
    for (int i = 0; i < 6; ++i)
        z[tid + 64 * i] = zbuf[b * 384 + tid + 64 * i];
    if (tid >= 1 && tid < T_S) perm[tid] = codes[tid * 64 + b];
    __syncthreads();

#pragma unroll
    for (int ii = 0; ii < 6; ++ii) {
        const int i  = tid + 64 * ii;
        const int t  = i / 12;
        const int j  = i - t * 12;
        const int k  = j >> 2;
        const int ch = j & 3;
        int p = k;
        if (t > 0) {
            const int code = perm[t];
            p = (k == 0) ? code / 9 : (k == 1) ? (code % 9) / 3 : code % 3;
        }
        zm[i] = z[t * 12 + p * 4 + ch];
    }
    __syncthreads();

#pragma unroll
    for (int ii = 0; ii < 6; ++ii) {
        const int i  = tid + 64 * ii;
        const int t  = i / 12;
        const int j  = i - t * 12;
        const int o  = j >> 2;
        const int cc = j & 1;
        const int mb = o * 4 + cc;
        const float pd = (t >= 1)  ? fabsf(zm[t * 12 + mb] - zm[(t - 1) * 12 + mb]) : 0.f;
        const float ad = (t <= 30) ? fabsf(zm[(t + 1) * 12 + mb] - zm[t * 12 + mb]) : 0.f;
        const bool  m  = (pd > 0.095f) && (ad > 0.095f);
        const float sm = (t >= 1 && t <= 30)
                             ? (zm[(t - 1) * 12 + j] + zm[(t + 1) * 12 + j]) * 0.5f
                             : 0.f;
        zf[i] = m ? sm : zm[t * 12 + j];
    }
    __syncthreads();

    for (int i = tid; i < 31 * 12; i += 64) {
        const int t  = i / 12;
        const int j  = i - t * 12;
        const int o  = j >> 2;
        const int c2 = j & 3;
        const int pb = o * 4 + 2 + (c2 & 1);
        float v;
        if (c2 < 2) v = zf[(t + 1) * 12 + pb] + 1.f;
        else        v = (zf[(t + 1) * 12 + pb] - zf[t * 12 + pb]) * 10.f;
        out[b * 372 + i] = v;
    }
}

extern "C" void kernel_launch(void* const* d_in, const int* in_sizes, int n_in,
                              void* d_out, int out_size, void* d_ws, size_t ws_size,
                              hipStream_t stream) {
    (void)in_sizes; (void)n_in; (void)out_size; (void)ws_size;
    const float* x     = (const float*)d_in[0];
    const float* W_enc = (const float*)d_in[1];
    const float* b_enc = (const float*)d_in[2];
    float* out  = (float*)d_out;

    float* zbuf   = (float*)d_ws;                   // 24576 floats
    float* Wt     = zbuf + ROWS * NCOL;             // 147456 floats
    float* part   = Wt + NCOL * DIM;                // 16*24576 floats
    float* zmatch = part + KSPL * ROWS * NCOL;      // 32*64*6 = 12288 floats
    int*   codes  = (int*)(zmatch + T_S * N_B * 6); // 2048 ints

    k_tw    <<<(NCOL * DIM) / 256, 256, 0, stream>>>(W_enc, Wt);
    k_gemm  <<<(ROWS / RPB) * KSPL, 256, 0, stream>>>(x, Wt, part);
    k_reduce<<<(ROWS * NCOL) / 256, 256, 0, stream>>>(part, b_enc, zbuf, zmatch);
    k_match <<<1, 64, 0, stream>>>(zmatch, codes);
    k_apply <<<N_B, 64, 0, stream>>>(zbuf, codes, out);
}

// Round 8
// 170.294 us; speedup vs baseline: 1.1195x; 1.0587x over previous
//
#include <hip/hip_runtime.h>

#define N_B   64
#define T_S   32
#define DIM   12288          // 3*64*64
#define ROWS  2048           // N_B*T_S
#define NCOL  12             // used GEMM columns (3 obj * 4)
#define RPW   4              // rows per wave
#define WAVES 4
#define RPB   (RPW * WAVES)  // 16 rows per block
#define KSPL  16             // split-K factor
#define KSEG  (DIM / KSPL)   // 768
#define JSTEP (KSEG / 256)   // 3 f4-steps per lane

// ---------------- Kernel 1: LDS-staged split-K skinny GEMM -----------------
// Grid: 2048 blocks = 128 row-groups x 16 k-segments.
// W segment staged to LDS once per block (direct from W, no transpose pass);
// the K-loop's global traffic is then a PURE x miss stream (12 hoisted
// dwordx4/thread) -> no L2-hit loads polluting the vmcnt queue.
__global__ __launch_bounds__(256) void k_gemm(const float* __restrict__ x,
                                              const float* __restrict__ W,
                                              float* __restrict__ part) {
    __shared__ float wt[NCOL * KSEG];      // [c][k] planes, 36 KB
    const int rb   = blockIdx.x >> 4;      // row group (0..127)
    const int sg   = blockIdx.x & 15;      // k segment (0..15)
    const int tid  = threadIdx.x;
    const int wave = tid >> 6;
    const int lane = tid & 63;
    const int r0   = rb * RPB + wave * RPW;
    const int k00  = sg * KSEG;

    // ---- stage W segment -> LDS: 2304 float4 global loads (L2-resident) ---
    // flat = 3*k + g ; g selects W col group {0..3, 8..11, 16..19} -> c=g*4..
#pragma unroll
    for (int it = 0; it < 9; ++it) {
        const int flat = tid + it * 256;           // 0..2303
        const int k    = flat / 3;
        const int g    = flat - 3 * k;
        const float4 wv = *(const float4*)(W + (size_t)(k00 + k) * 24 + g * 8);
        float* d = wt + (g * 4) * KSEG + k;        // 4 scalar writes, ~3-way bank
        d[0 * KSEG] = wv.x;
        d[1 * KSEG] = wv.y;
        d[2 * KSEG] = wv.z;
        d[3 * KSEG] = wv.w;
    }

    // ---- issue ALL x loads (pure HBM-miss stream) -------------------------
    float4 xv[JSTEP][RPW];
#pragma unroll
    for (int j = 0; j < JSTEP; ++j)
#pragma unroll
        for (int r = 0; r < RPW; ++r)
            xv[j][r] = *(const float4*)(x + (size_t)(r0 + r) * DIM + k00 + j * 256 + lane * 4);

    __syncthreads();   // drains staging + x loads, overlapped across waves

    float acc[RPW][NCOL];
#pragma unroll
    for (int r = 0; r < RPW; ++r)
#pragma unroll
        for (int c = 0; c < NCOL; ++c) acc[r][c] = 0.f;

#pragma unroll
    for (int j = 0; j < JSTEP; ++j) {
        const int kl = j * 256 + lane * 4;         // local k of this lane's 4
#pragma unroll
        for (int c = 0; c < NCOL; ++c) {
            const float4 wv = *(const float4*)(wt + c * KSEG + kl);  // ds_read_b128, conflict-free
#pragma unroll
            for (int r = 0; r < RPW; ++r)
                acc[r][c] += xv[j][r].x * wv.x + xv[j][r].y * wv.y +
                             xv[j][r].z * wv.z + xv[j][r].w * wv.w;
        }
    }

    // wave butterfly: sum each accumulator across 64 lanes
#pragma unroll
    for (int r = 0; r < RPW; ++r)
#pragma unroll
        for (int c = 0; c < NCOL; ++c) {
            float v = acc[r][c];
            v += __shfl_xor(v, 32, 64);
            v += __shfl_xor(v, 16, 64);
            v += __shfl_xor(v, 8, 64);
            v += __shfl_xor(v, 4, 64);
            v += __shfl_xor(v, 2, 64);
            v += __shfl_xor(v, 1, 64);
            acc[r][c] = v;
        }

    __syncthreads();                       // reuse wt's LDS for the reduce
    float* red = wt;                       // 192 floats needed
    if (lane == 0) {
#pragma unroll
        for (int r = 0; r < RPW; ++r)
#pragma unroll
            for (int c = 0; c < NCOL; ++c)
                red[(wave * RPW + r) * NCOL + c] = acc[r][c];
    }
    __syncthreads();

    if (tid < RPB * NCOL)
        part[(size_t)sg * (ROWS * NCOL) + (size_t)rb * (RPB * NCOL) + tid] = red[tid];
}

// ---------------- Kernel 2: reduce split-K + bias + sigmoid constrain ------
__global__ __launch_bounds__(256) void k_reduce(const float* __restrict__ part,
                                                const float* __restrict__ b_enc,
                                                float* __restrict__ zbuf) {
    const int rc = blockIdx.x * 256 + threadIdx.x;    // 0..24575 = row*12+c
    float s = 0.f;
#pragma unroll
    for (int i = 0; i < KSPL; ++i) s += part[(size_t)i * (ROWS * NCOL) + rc];

    const int row = rc / NCOL;
    const int c   = rc - row * NCOL;
    const int o   = c >> 2;
    const int cp  = c & 3;
    s += b_enc[o * 8 + cp];
    const float sg = 1.f / (1.f + expf(-s));
    float v;
    if (cp == 0)      v = sg * 0.7f + 0.1f;
    else if (cp == 1) v = sg * 0.5f + 0.75f;
    else              v = (2.f * sg - 1.f) * 0.9f;
    zbuf[rc] = v;
}

// ---------------- Kernel 3: match + fix_supair + output --------------------
__global__ __launch_bounds__(64) void k_post(const float* __restrict__ zbuf,
                                             float* __restrict__ out) {
    __shared__ float z[T_S * NCOL];
    __shared__ float zm[T_S * NCOL];
    __shared__ float zf[T_S * NCOL];
    __shared__ int   perm[T_S];
    const int b   = blockIdx.x;
    const int tid = threadIdx.x;

#pragma unroll
    for (int i = 0; i < 6; ++i)
        z[tid + 64 * i] = zbuf[b * 384 + tid + 64 * i];
    __syncthreads();

    if (tid == 0) {
        float px0 = z[2],  py0 = z[3];
        float px1 = z[6],  py1 = z[7];
        float px2 = z[10], py2 = z[11];
        for (int t = 1; t < T_S; ++t) {
            const int base = t * 12;
            const float cx0 = z[base + 2],  cy0 = z[base + 3];
            const float cx1 = z[base + 6],  cy1 = z[base + 7];
            const float cx2 = z[base + 10], cy2 = z[base + 11];

            float dx, dy;
            dx = px0 - cx0; dy = py0 - cy0; const float e00 = dx * dx + dy * dy;
            dx = px0 - cx1; dy = py0 - cy1; const float e01 = dx * dx + dy * dy;
            dx = px0 - cx2; dy = py0 - cy2; const float e02 = dx * dx + dy * dy;
            dx = px1 - cx0; dy = py1 - cy0; const float e10 = dx * dx + dy * dy;
            dx = px1 - cx1; dy = py1 - cy1; const float e11 = dx * dx + dy * dy;
            dx = px1 - cx2; dy = py1 - cy2; const float e12 = dx * dx + dy * dy;
            dx = px2 - cx0; dy = py2 - cy0; const float e20 = dx * dx + dy * dy;
            dx = px2 - cx1; dy = py2 - cy1; const float e21 = dx * dx + dy * dy;
            dx = px2 - cx2; dy = py2 - cy2; const float e22 = dx * dx + dy * dy;

            auto amin3 = [](float a0, float a1, float a2) {
                int j = 0; float e = a0;
                if (a1 < e) { e = a1; j = 1; }
                if (a2 < e) { j = 2; }
                return j;
            };
            int i0 = amin3(e00, e01, e02);
            int i1 = amin3(e10, e11, e12);
            int i2 = amin3(e20, e21, e22);
            const bool ok = (i1 != i0) && (i2 != i1) && (i0 != i2);
            if (!ok) {
                float u0 = 0.f, u1 = 0.f, u2 = 0.f;
                i0 = amin3(e00, e01, e02);
                if (i0 == 0) u0 = 1.f; else if (i0 == 1) u1 = 1.f; else u2 = 1.f;
                i1 = amin3(e10 + u0 * 1e12f, e11 + u1 * 1e12f, e12 + u2 * 1e12f);
                if (i1 == 0) u0 = 1.f; else if (i1 == 1) u1 = 1.f; else u2 = 1.f;
                i2 = amin3(e20 + u0 * 1e12f, e21 + u1 * 1e12f, e22 + u2 * 1e12f);
            }
            perm[t] = i0 * 9 + i1 * 3 + i2;
            px0 = (i0 == 0) ? cx0 : (i0 == 1) ? cx1 : cx2;
            py0 = (i0 == 0) ? cy0 : (i0 == 1) ? cy1 : cy2;
            px1 = (i1 == 0) ? cx0 : (i1 == 1) ? cx1 : cx2;
            py1 = (i1 == 0) ? cy0 : (i1 == 1) ? cy1 : cy2;
            px2 = (i2 == 0) ? cx0 : (i2 == 1) ? cx1 : cx2;
            py2 = (i2 == 0) ? cy0 : (i2 == 1) ? cy1 : cy2;
        }
    }
    __syncthreads();

#pragma unroll
    for (int ii = 0; ii < 6; ++ii) {
        const int i  = tid + 64 * ii;
        const int t  = i / 12;
        const int j  = i - t * 12;
        const int k  = j >> 2;
        const int ch = j & 3;
        int p = k;
        if (t > 0) {
            const int code = perm[t];
            p = (k == 0) ? code / 9 : (k == 1) ? (code % 9) / 3 : code % 3;
        }
        zm[i] = z[t * 12 + p * 4 + ch];
    }
    __syncthreads();

#pragma unroll
    for (int ii = 0; ii < 6; ++ii) {
        const int i  = tid + 64 * ii;
        const int t  = i / 12;
        const int j  = i - t * 12;
        const int o  = j >> 2;
        const int cc = j & 1;
        const int mb = o * 4 + cc;
        const float pd = (t >= 1)  ? fabsf(zm[t * 12 + mb] - zm[(t - 1) * 12 + mb]) : 0.f;
        const float ad = (t <= 30) ? fabsf(zm[(t + 1) * 12 + mb] - zm[t * 12 + mb]) : 0.f;
        const bool  m  = (pd > 0.095f) && (ad > 0.095f);
        const float sm = (t >= 1 && t <= 30)
                             ? (zm[(t - 1) * 12 + j] + zm[(t + 1) * 12 + j]) * 0.5f
                             : 0.f;
        zf[i] = m ? sm : zm[t * 12 + j];
    }
    __syncthreads();

    for (int i = tid; i < 31 * 12; i += 64) {
        const int t  = i / 12;
        const int j  = i - t * 12;
        const int o  = j >> 2;
        const int c2 = j & 3;
        const int pb = o * 4 + 2 + (c2 & 1);
        float v;
        if (c2 < 2) v = zf[(t + 1) * 12 + pb] + 1.f;
        else        v = (zf[(t + 1) * 12 + pb] - zf[t * 12 + pb]) * 10.f;
        out[b * 372 + i] = v;
    }
}

extern "C" void kernel_launch(void* const* d_in, const int* in_sizes, int n_in,
                              void* d_out, int out_size, void* d_ws, size_t ws_size,
                              hipStream_t stream) {
    (void)in_sizes; (void)n_in; (void)out_size; (void)ws_size;
    const float* x     = (const float*)d_in[0];
    const float* W_enc = (const float*)d_in[1];
    const float* b_enc = (const float*)d_in[2];
    float* out  = (float*)d_out;

    float* zbuf = (float*)d_ws;                     // 24576 floats
    float* part = zbuf + ROWS * NCOL;               // 16*24576 floats

    k_gemm  <<<(ROWS / RPB) * KSPL, 256, 0, stream>>>(x, W_enc, part);
    k_reduce<<<(ROWS * NCOL) / 256, 256, 0, stream>>>(part, b_enc, zbuf);
    k_post  <<<N_B, 64, 0, stream>>>(zbuf, out);
}